// Round 6
// baseline (245.348 us; speedup 1.0000x reference)
//
#include <hip/hip_runtime.h>
#include <hip/hip_bf16.h>

typedef __attribute__((ext_vector_type(4))) float f32x4;
typedef __attribute__((ext_vector_type(8))) short bf16x8;
typedef __attribute__((ext_vector_type(4))) unsigned short u16x4;

#define DEVI __device__ __forceinline__

constexpr int B_ = 4, S_ = 1024, D_ = 512, H_ = 8, HD_ = 64;
constexpr float CSH = 11.0903548f;  // fixed softmax shift (folded into bias table)

DEVI unsigned short f2b(float f) {
  union { float f; unsigned u; } v; v.f = f;
  unsigned r = v.u + 0x7fffu + ((v.u >> 16) & 1u);
  return (unsigned short)(r >> 16);
}

DEVI float b2f(unsigned short u) {
  union { unsigned u; float f; } v; v.u = ((unsigned)u) << 16;
  return v.f;
}

// ---------------- prep: weight transpose+bf16 (z=0..3) and bias MLP table (z=4) ----------------
__global__ __launch_bounds__(256) void k_prep(const float* Wa, const float* Wb,
                                              const float* Wc, const float* Wd,
                                              unsigned short* T0, unsigned short* T1,
                                              unsigned short* T2, unsigned short* T3,
                                              const float* mW1, const float* mb1,
                                              const float* mW2, const float* mb2,
                                              float* table) {
  if (blockIdx.z == 4) {
    if (blockIdx.y != 0) return;
    int idx = blockIdx.x * 256 + threadIdx.x;
    if (idx >= 63 * 63) return;
    int dy = idx / 63 - 31, dx = idx % 63 - 31;
    float r0 = copysignf(log1pf(fabsf((float)dy)), (float)dy);
    float r1 = copysignf(log1pf(fabsf((float)dx)), (float)dx);
    float acc[8];
#pragma unroll
    for (int h = 0; h < 8; ++h) acc[h] = mb2[h];
    for (int j = 0; j < 128; ++j) {
      float hv = fmaxf(r0 * mW1[j] + r1 * mW1[128 + j] + mb1[j], 0.f);
#pragma unroll
      for (int h = 0; h < 8; ++h) acc[h] += hv * mW2[j * 8 + h];
    }
#pragma unroll
    for (int h = 0; h < 8; ++h) table[h * 3969 + idx] = acc[h] - CSH;  // shift folded in
    return;
  }
  const float* W = blockIdx.z == 0 ? Wa : blockIdx.z == 1 ? Wb : blockIdx.z == 2 ? Wc : Wd;
  unsigned short* T = blockIdx.z == 0 ? T0 : blockIdx.z == 1 ? T1 : blockIdx.z == 2 ? T2 : T3;
  __shared__ float tile[32][33];
  int tx = threadIdx.x & 31, ty = threadIdx.x >> 5;
  int n0 = blockIdx.x * 32, k0 = blockIdx.y * 32;
#pragma unroll
  for (int r = 0; r < 4; ++r) tile[ty + r * 8][tx] = W[(size_t)(k0 + ty + r * 8) * D_ + n0 + tx];
  __syncthreads();
#pragma unroll
  for (int r = 0; r < 4; ++r) T[(size_t)(n0 + ty + r * 8) * D_ + k0 + tx] = f2b(tile[tx][ty + r * 8]);
}

// ---------------- merged QKV GEMM, 64x128 tiles, BK=64; V written pre-transposed ----------------
__global__ __launch_bounds__(256) void k_gemm_qkv(const float* Aq, const float* Ak, const float* Av,
                                                  const unsigned short* Tq, const unsigned short* Tk,
                                                  const unsigned short* Tv,
                                                  const float* bqv, const float* bkv, const float* bvv,
                                                  unsigned short* Oq, unsigned short* Ok,
                                                  unsigned short* OvT) {
  const float* A = blockIdx.z == 0 ? Aq : blockIdx.z == 1 ? Ak : Av;
  const unsigned short* BT = blockIdx.z == 0 ? Tq : blockIdx.z == 1 ? Tk : Tv;
  const float* bias = blockIdx.z == 0 ? bqv : blockIdx.z == 1 ? bkv : bvv;

  __shared__ unsigned short As[64][72];   // +8 pad: 144B row stride
  __shared__ unsigned short Bs[128][72];
  const int tid = threadIdx.x;
  const int lane = tid & 63, wave = tid >> 6;
  const int lr = lane & 15, lg = lane >> 4;
  const int wm = (wave >> 1) * 32, wn = (wave & 1) * 64;
  const int m0 = blockIdx.x * 64, n0 = blockIdx.y * 128;

  f32x4 acc[2][4];
#pragma unroll
  for (int i = 0; i < 2; ++i)
#pragma unroll
    for (int j = 0; j < 4; ++j) acc[i][j] = (f32x4){0.f, 0.f, 0.f, 0.f};

  for (int k0 = 0; k0 < 512; k0 += 64) {
#pragma unroll
    for (int i = 0; i < 4; ++i) {   // A: 64 rows x 16 float4 chunks = 1024 tasks
      int idx = tid + i * 256;
      int r = idx >> 4, c4 = (idx & 15) * 4;
      float4 fv = *(const float4*)(A + (size_t)(m0 + r) * 512 + k0 + c4);
      u16x4 wv;
      wv[0] = f2b(fv.x); wv[1] = f2b(fv.y); wv[2] = f2b(fv.z); wv[3] = f2b(fv.w);
      *(u16x4*)&As[r][c4] = wv;
    }
#pragma unroll
    for (int i = 0; i < 8; ++i) {   // B: 128 rows x 16 u16x4 chunks = 2048 tasks
      int idx = tid + i * 256;
      int r = idx >> 4, c4 = (idx & 15) * 4;
      *(u16x4*)&Bs[r][c4] = *(const u16x4*)(BT + (size_t)(n0 + r) * 512 + k0 + c4);
    }
    __syncthreads();
#pragma unroll
    for (int kk = 0; kk < 2; ++kk) {
      bf16x8 af[2], bg[4];
#pragma unroll
      for (int i = 0; i < 2; ++i) af[i] = *(const bf16x8*)&As[wm + i * 16 + lr][kk * 32 + lg * 8];
#pragma unroll
      for (int j = 0; j < 4; ++j) bg[j] = *(const bf16x8*)&Bs[wn + j * 16 + lr][kk * 32 + lg * 8];
#pragma unroll
      for (int i = 0; i < 2; ++i)
#pragma unroll
        for (int j = 0; j < 4; ++j)
          acc[i][j] = __builtin_amdgcn_mfma_f32_16x16x32_bf16(af[i], bg[j], acc[i][j], 0, 0, 0);
    }
    __syncthreads();
  }

#pragma unroll
  for (int i = 0; i < 2; ++i)
#pragma unroll
    for (int j = 0; j < 4; ++j) {
      int mbase = m0 + wm + i * 16 + lg * 4;
      int n = n0 + wn + j * 16 + lr;
      float bvl = bias[n];
      int h = n >> 6, hd = n & 63;
      int bseg = mbase >> 10, s0 = mbase & 1023;
      if (blockIdx.z == 2) {
        u16x4 pk;
#pragma unroll
        for (int r = 0; r < 4; ++r) pk[r] = f2b(acc[i][j][r] + bvl);
        *(u16x4*)(OvT + (((size_t)(bseg * H_ + h) * 64 + hd) * 1024 + s0)) = pk;
      } else {
        unsigned short* outp = blockIdx.z == 0 ? Oq : Ok;
#pragma unroll
        for (int r = 0; r < 4; ++r) {
          float v = acc[i][j][r] + bvl;
          outp[(((size_t)bseg * H_ + h) * S_ + s0 + r) * HD_ + hd] = f2b(v);
        }
      }
    }
}

// ---------------- output projection GEMM, 64x128 tiles, BK=64: bf16 A @ W^T + bias -> fp32 ----------------
__global__ __launch_bounds__(256) void k_gemm_out(const unsigned short* A, const unsigned short* BT,
                                                  const float* bias, float* outp) {
  __shared__ unsigned short As[64][72];
  __shared__ unsigned short Bs[128][72];
  const int tid = threadIdx.x;
  const int lane = tid & 63, wave = tid >> 6;
  const int lr = lane & 15, lg = lane >> 4;
  const int wm = (wave >> 1) * 32, wn = (wave & 1) * 64;
  const int m0 = blockIdx.x * 64, n0 = blockIdx.y * 128;

  f32x4 acc[2][4];
#pragma unroll
  for (int i = 0; i < 2; ++i)
#pragma unroll
    for (int j = 0; j < 4; ++j) acc[i][j] = (f32x4){0.f, 0.f, 0.f, 0.f};

  for (int k0 = 0; k0 < 512; k0 += 64) {
#pragma unroll
    for (int i = 0; i < 4; ++i) {
      int idx = tid + i * 256;
      int r = idx >> 4, c4 = (idx & 15) * 4;
      *(u16x4*)&As[r][c4] = *(const u16x4*)(A + (size_t)(m0 + r) * 512 + k0 + c4);
    }
#pragma unroll
    for (int i = 0; i < 8; ++i) {
      int idx = tid + i * 256;
      int r = idx >> 4, c4 = (idx & 15) * 4;
      *(u16x4*)&Bs[r][c4] = *(const u16x4*)(BT + (size_t)(n0 + r) * 512 + k0 + c4);
    }
    __syncthreads();
#pragma unroll
    for (int kk = 0; kk < 2; ++kk) {
      bf16x8 af[2], bg[4];
#pragma unroll
      for (int i = 0; i < 2; ++i) af[i] = *(const bf16x8*)&As[wm + i * 16 + lr][kk * 32 + lg * 8];
#pragma unroll
      for (int j = 0; j < 4; ++j) bg[j] = *(const bf16x8*)&Bs[wn + j * 16 + lr][kk * 32 + lg * 8];
#pragma unroll
      for (int i = 0; i < 2; ++i)
#pragma unroll
        for (int j = 0; j < 4; ++j)
          acc[i][j] = __builtin_amdgcn_mfma_f32_16x16x32_bf16(af[i], bg[j], acc[i][j], 0, 0, 0);
    }
    __syncthreads();
  }

#pragma unroll
  for (int i = 0; i < 2; ++i)
#pragma unroll
    for (int j = 0; j < 4; ++j) {
      int mbase = m0 + wm + i * 16 + lg * 4;
      int n = n0 + wn + j * 16 + lr;
      float bvl = bias[n];
#pragma unroll
      for (int r = 0; r < 4; ++r)
        outp[(size_t)(mbase + r) * 512 + n] = acc[i][j][r] + bvl;
    }
}

// ---------------- fused SINGLE-PASS attention: unnormalized P' kept in registers (bf16) ----------------
// 256 thr / 4 waves / 64 q-rows per block; K/V double-buffered, 1 barrier/tile.
// NOTE on layouts (swapped QK^T): S^T fragment col (=lr) is the q-row for P/ls;
// PV output fragment row (=lg*4+r) is the q-row for O. The O-normalizer must be
// gathered from the lane holding that row's ls (lane lg*4+r) — see invq below.
__global__ __launch_bounds__(256, 2) void k_attn(const unsigned short* Qb, const unsigned short* Kb,
                                                 const unsigned short* VT, const float* tbl,
                                                 const int* mask, float* out_attn,
                                                 unsigned short* Xp) {
  const int tid = threadIdx.x;
  const int lane = tid & 63, w = tid >> 6;
  const int lr = lane & 15, lg = lane >> 4;
  const int bh = blockIdx.y, b = bh >> 3, h = bh & 7;
  const int q0 = blockIdx.x * 64;

  __shared__ unsigned short Ks[2][64][64];   // K tiles, dbuf, XOR-swizzled 16B chunks
  __shared__ unsigned short Vt[2][64][64];   // V^T tiles, dbuf, same swizzle
  __shared__ unsigned short Pl[4][16][64];   // per-wave P tile
  __shared__ float biasT[3969];
  __shared__ float mbig[1024];
  __shared__ int tbad[16];

  const unsigned short* Qh = Qb + (size_t)bh * (S_ * HD_);
  const unsigned short* Kh = Kb + (size_t)bh * (S_ * HD_);
  const unsigned short* Vth = VT + (size_t)bh * (HD_ * S_);

  const int srow = tid >> 3, sc = tid & 7;         // 32 rows per pass; rows srow and srow+32
  const int swz = (sc ^ (srow & 7)) * 8;           // (srow+32)&7 == srow&7

  if (tid < 16) tbad[tid] = 0;
  __syncthreads();
  for (int i = tid; i < 3969; i += 256) biasT[i] = tbl[h * 3969 + i];
  {
    int4 mv = *(const int4*)(mask + b * S_ + tid * 4);
    int base = tid * 4;
    // masked sentinel -30: finite, below any real arg, exact uniform-row limit
    // when a row is fully masked (matches reference softmax of constant row).
    mbig[base] = mv.x ? 3.0e38f : -30.f;
    mbig[base + 1] = mv.y ? 3.0e38f : -30.f;
    mbig[base + 2] = mv.z ? 3.0e38f : -30.f;
    mbig[base + 3] = mv.w ? 3.0e38f : -30.f;
    if (!(mv.x && mv.y && mv.z && mv.w)) tbad[base >> 6] = 1;
  }
  // prologue: K tile 0, V tile 0
  *(bf16x8*)&Ks[0][srow][swz] = *(const bf16x8*)(Kh + (size_t)srow * 64 + sc * 8);
  *(bf16x8*)&Ks[0][srow + 32][swz] = *(const bf16x8*)(Kh + (size_t)(srow + 32) * 64 + sc * 8);
  *(bf16x8*)&Vt[0][srow][swz] = *(const bf16x8*)(Vth + (size_t)srow * S_ + sc * 8);
  *(bf16x8*)&Vt[0][srow + 32][swz] = *(const bf16x8*)(Vth + (size_t)(srow + 32) * S_ + sc * 8);

  const int qrow = q0 + w * 16 + lr;
  const bf16x8 bq0 = *(const bf16x8*)(Qh + (size_t)qrow * 64 + lg * 8);
  const bf16x8 bq1 = *(const bf16x8*)(Qh + (size_t)qrow * 64 + 32 + lg * 8);
  const int qterm = (qrow >> 5) * 63 + (qrow & 31) + 1984;

  u16x4 preg[16][4];   // unnormalized P' (bf16), statically indexed via full unroll
  f32x4 of[4];
#pragma unroll
  for (int i = 0; i < 4; ++i) of[i] = (f32x4){0.f, 0.f, 0.f, 0.f};
  float ls = 0.f;
  __syncthreads();

  // ---- SINGLE PASS: QK^T -> exp (unnormalized) -> keep in regs + accumulate sum + PV ----
#pragma unroll
  for (int kt = 0; kt < 16; ++kt) {
    const int cur = kt & 1;
    bf16x8 nk0, nk1, nv0, nv1;
    if (kt < 15) {
      nk0 = *(const bf16x8*)(Kh + (size_t)((kt + 1) * 64 + srow) * 64 + sc * 8);
      nk1 = *(const bf16x8*)(Kh + (size_t)((kt + 1) * 64 + srow + 32) * 64 + sc * 8);
      nv0 = *(const bf16x8*)(Vth + (size_t)srow * S_ + (kt + 1) * 64 + sc * 8);
      nv1 = *(const bf16x8*)(Vth + (size_t)(srow + 32) * S_ + (kt + 1) * 64 + sc * 8);
    }
    const int bidx = qterm - 126 * kt;
    const bool bad = tbad[kt] != 0;
#pragma unroll
    for (int fn = 0; fn < 4; ++fn) {
      const unsigned short* krow = &Ks[cur][fn * 16 + lr][0];
      bf16x8 a0 = *(const bf16x8*)(krow + (lg ^ (lr & 7)) * 8);
      bf16x8 a1 = *(const bf16x8*)(krow + ((4 + lg) ^ (lr & 7)) * 8);
      f32x4 s = (f32x4){0.f, 0.f, 0.f, 0.f};
      s = __builtin_amdgcn_mfma_f32_16x16x32_bf16(a0, bq0, s, 0, 0, 0);
      s = __builtin_amdgcn_mfma_f32_16x16x32_bf16(a1, bq1, s, 0, 0, 0);
      const int kob = fn * 16 + lg * 4;
      const int ib = bidx - kob - (fn >= 2 ? 31 : 0);
      u16x4 pb;
#pragma unroll
      for (int r = 0; r < 4; ++r) {
        float arg = fmaf(s[r], 0.125f, biasT[ib - r]);
        if (bad) arg = fminf(arg, mbig[kt * 64 + kob + r]);
        float p = __expf(arg);       // unnormalized
        ls += p;
        pb[r] = f2b(p);
      }
      preg[kt][fn] = pb;
      *(u16x4*)((char*)&Pl[w][lr][0] + ((fn * 2 + (lg >> 1)) ^ (lr & 7)) * 16 + (lg & 1) * 8) = pb;
    }
    // PV with unnormalized P' (normalization deferred to epilogue scale)
#pragma unroll
    for (int c = 0; c < 2; ++c) {
      bf16x8 pa = *(const bf16x8*)((const char*)&Pl[w][lr][0] + ((c * 4 + lg) ^ (lr & 7)) * 16);
#pragma unroll
      for (int fn2 = 0; fn2 < 4; ++fn2) {
        const unsigned short* vrow = &Vt[cur][fn2 * 16 + lr][0];
        bf16x8 bv = *(const bf16x8*)((const char*)vrow + ((c * 4 + lg) ^ (lr & 7)) * 16);
        of[fn2] = __builtin_amdgcn_mfma_f32_16x16x32_bf16(pa, bv, of[fn2], 0, 0, 0);
      }
    }
    if (kt < 15) {
      *(bf16x8*)&Ks[cur ^ 1][srow][swz] = nk0;
      *(bf16x8*)&Ks[cur ^ 1][srow + 32][swz] = nk1;
      *(bf16x8*)&Vt[cur ^ 1][srow][swz] = nv0;
      *(bf16x8*)&Vt[cur ^ 1][srow + 32][swz] = nv1;
    }
    __syncthreads();
  }

  // row-sum across lg groups (lanes lr, lr+16, lr+32, lr+48 share q-row qrow)
  ls += __shfl_xor(ls, 16, 64);
  ls += __shfl_xor(ls, 32, 64);
  const float inv = 1.f / ls;   // normalizer for q-row q0 + w*16 + lr

  // normalizers for the PV output rows: of[.][r] belongs to q-row q0+w*16+lg*4+r,
  // whose ls lives in lane (lg*4+r) (its lr == lg*4+r; all lg copies identical).
  f32x4 invq;
#pragma unroll
  for (int r = 0; r < 4; ++r) invq[r] = __shfl(inv, lg * 4 + r, 64);

  // ---- epilogue A: normalized attention matrix, coalesced f32x4 stores ----
  float* oa = out_attn + (size_t)bh * (S_ * S_) + (size_t)qrow * S_;
#pragma unroll
  for (int kt = 0; kt < 16; ++kt) {
#pragma unroll
    for (int fn = 0; fn < 4; ++fn) {
      u16x4 pb = preg[kt][fn];
      f32x4 pr;
#pragma unroll
      for (int r = 0; r < 4; ++r) pr[r] = b2f(pb[r]) * inv;
      *(f32x4*)(oa + kt * 64 + fn * 16 + lg * 4) = pr;
    }
  }

  // ---- epilogue B: x pre-projection, bf16 [B,S,D]; scale O rows by their own inv ----
#pragma unroll
  for (int fn2 = 0; fn2 < 4; ++fn2)
#pragma unroll
    for (int r = 0; r < 4; ++r) {
      int q = q0 + w * 16 + lg * 4 + r;
      Xp[((size_t)b * S_ + q) * D_ + h * 64 + fn2 * 16 + lr] = f2b(of[fn2][r] * invq[r]);
    }
}

// ---------------- host launch ----------------
extern "C" void kernel_launch(void* const* d_in, const int* in_sizes, int n_in,
                              void* d_out, int out_size, void* d_ws, size_t ws_size,
                              hipStream_t stream) {
  const float* query = (const float*)d_in[0];
  const float* key   = (const float*)d_in[1];
  const float* value = (const float*)d_in[2];
  const int*   maskp = (const int*)d_in[3];
  const float* Wq = (const float*)d_in[4];
  const float* bq = (const float*)d_in[5];
  const float* Wk = (const float*)d_in[6];
  const float* bk = (const float*)d_in[7];
  const float* Wv = (const float*)d_in[8];
  const float* bv = (const float*)d_in[9];
  const float* Wo = (const float*)d_in[10];
  const float* bo = (const float*)d_in[11];
  const float* W1 = (const float*)d_in[12];
  const float* b1 = (const float*)d_in[13];
  const float* W2 = (const float*)d_in[14];
  const float* b2 = (const float*)d_in[15];

  char* ws = (char*)d_ws;
  const size_t MB4 = (size_t)4 * 1024 * 1024;
  unsigned short* Qb  = (unsigned short*)(ws);
  unsigned short* Kb  = (unsigned short*)(ws + MB4);
  unsigned short* VT  = (unsigned short*)(ws + 2 * MB4);
  unsigned short* Xp  = (unsigned short*)(ws + 3 * MB4);
  unsigned short* WqT = (unsigned short*)(ws + 4 * MB4);
  unsigned short* WkT = (unsigned short*)(ws + 4 * MB4 + 524288);
  unsigned short* WvT = (unsigned short*)(ws + 4 * MB4 + 2 * 524288);
  unsigned short* WoT = (unsigned short*)(ws + 4 * MB4 + 3 * 524288);
  float* table        = (float*)(ws + 4 * MB4 + 4 * 524288);

  float* out_x = (float*)d_out;
  float* out_attn = out_x + (size_t)B_ * S_ * D_;

  k_prep<<<dim3(16, 16, 5), 256, 0, stream>>>(Wq, Wk, Wv, Wo, WqT, WkT, WvT, WoT,
                                              W1, b1, W2, b2, table);
  k_gemm_qkv<<<dim3(64, 4, 3), 256, 0, stream>>>(query, key, value, WqT, WkT, WvT,
                                                 bq, bk, bv, Qb, Kb, VT);
  k_attn<<<dim3(16, 32), 256, 0, stream>>>(Qb, Kb, VT, table, maskp, out_attn, Xp);
  k_gemm_out<<<dim3(64, 4), 256, 0, stream>>>(Xp, WoT, bo, out_x);
}

// Round 7
// 143.997 us; speedup vs baseline: 1.7038x; 1.7038x over previous
//
#include <hip/hip_runtime.h>
#include <hip/hip_bf16.h>

typedef __attribute__((ext_vector_type(4))) float f32x4;
typedef __attribute__((ext_vector_type(8))) short bf16x8;
typedef __attribute__((ext_vector_type(4))) unsigned short u16x4;

#define DEVI __device__ __forceinline__

constexpr int B_ = 4, S_ = 1024, D_ = 512, H_ = 8, HD_ = 64;
constexpr float CSH = 11.0903548f;  // fixed softmax shift (folded into bias table)

DEVI unsigned short f2b(float f) {
  union { float f; unsigned u; } v; v.f = f;
  unsigned r = v.u + 0x7fffu + ((v.u >> 16) & 1u);
  return (unsigned short)(r >> 16);
}

DEVI float b2f(unsigned short u) {
  union { unsigned u; float f; } v; v.u = ((unsigned)u) << 16;
  return v.f;
}

// ---------------- prep: weight transpose+bf16 (z=0..3) and bias MLP table (z=4) ----------------
__global__ __launch_bounds__(256) void k_prep(const float* Wa, const float* Wb,
                                              const float* Wc, const float* Wd,
                                              unsigned short* T0, unsigned short* T1,
                                              unsigned short* T2, unsigned short* T3,
                                              const float* mW1, const float* mb1,
                                              const float* mW2, const float* mb2,
                                              float* table) {
  if (blockIdx.z == 4) {
    if (blockIdx.y != 0) return;
    int idx = blockIdx.x * 256 + threadIdx.x;
    if (idx >= 63 * 63) return;
    int dy = idx / 63 - 31, dx = idx % 63 - 31;
    float r0 = copysignf(log1pf(fabsf((float)dy)), (float)dy);
    float r1 = copysignf(log1pf(fabsf((float)dx)), (float)dx);
    float acc[8];
#pragma unroll
    for (int h = 0; h < 8; ++h) acc[h] = mb2[h];
    for (int j = 0; j < 128; ++j) {
      float hv = fmaxf(r0 * mW1[j] + r1 * mW1[128 + j] + mb1[j], 0.f);
#pragma unroll
      for (int h = 0; h < 8; ++h) acc[h] += hv * mW2[j * 8 + h];
    }
#pragma unroll
    for (int h = 0; h < 8; ++h) table[h * 3969 + idx] = acc[h] - CSH;  // shift folded in
    return;
  }
  const float* W = blockIdx.z == 0 ? Wa : blockIdx.z == 1 ? Wb : blockIdx.z == 2 ? Wc : Wd;
  unsigned short* T = blockIdx.z == 0 ? T0 : blockIdx.z == 1 ? T1 : blockIdx.z == 2 ? T2 : T3;
  __shared__ float tile[32][33];
  int tx = threadIdx.x & 31, ty = threadIdx.x >> 5;
  int n0 = blockIdx.x * 32, k0 = blockIdx.y * 32;
#pragma unroll
  for (int r = 0; r < 4; ++r) tile[ty + r * 8][tx] = W[(size_t)(k0 + ty + r * 8) * D_ + n0 + tx];
  __syncthreads();
#pragma unroll
  for (int r = 0; r < 4; ++r) T[(size_t)(n0 + ty + r * 8) * D_ + k0 + tx] = f2b(tile[tx][ty + r * 8]);
}

// ---------------- merged QKV GEMM, 64x128 tiles, BK=64; V written pre-transposed ----------------
__global__ __launch_bounds__(256) void k_gemm_qkv(const float* Aq, const float* Ak, const float* Av,
                                                  const unsigned short* Tq, const unsigned short* Tk,
                                                  const unsigned short* Tv,
                                                  const float* bqv, const float* bkv, const float* bvv,
                                                  unsigned short* Oq, unsigned short* Ok,
                                                  unsigned short* OvT) {
  const float* A = blockIdx.z == 0 ? Aq : blockIdx.z == 1 ? Ak : Av;
  const unsigned short* BT = blockIdx.z == 0 ? Tq : blockIdx.z == 1 ? Tk : Tv;
  const float* bias = blockIdx.z == 0 ? bqv : blockIdx.z == 1 ? bkv : bvv;

  __shared__ unsigned short As[64][72];   // +8 pad: 144B row stride
  __shared__ unsigned short Bs[128][72];
  const int tid = threadIdx.x;
  const int lane = tid & 63, wave = tid >> 6;
  const int lr = lane & 15, lg = lane >> 4;
  const int wm = (wave >> 1) * 32, wn = (wave & 1) * 64;
  const int m0 = blockIdx.x * 64, n0 = blockIdx.y * 128;

  f32x4 acc[2][4];
#pragma unroll
  for (int i = 0; i < 2; ++i)
#pragma unroll
    for (int j = 0; j < 4; ++j) acc[i][j] = (f32x4){0.f, 0.f, 0.f, 0.f};

  for (int k0 = 0; k0 < 512; k0 += 64) {
#pragma unroll
    for (int i = 0; i < 4; ++i) {   // A: 64 rows x 16 float4 chunks = 1024 tasks
      int idx = tid + i * 256;
      int r = idx >> 4, c4 = (idx & 15) * 4;
      float4 fv = *(const float4*)(A + (size_t)(m0 + r) * 512 + k0 + c4);
      u16x4 wv;
      wv[0] = f2b(fv.x); wv[1] = f2b(fv.y); wv[2] = f2b(fv.z); wv[3] = f2b(fv.w);
      *(u16x4*)&As[r][c4] = wv;
    }
#pragma unroll
    for (int i = 0; i < 8; ++i) {   // B: 128 rows x 16 u16x4 chunks = 2048 tasks
      int idx = tid + i * 256;
      int r = idx >> 4, c4 = (idx & 15) * 4;
      *(u16x4*)&Bs[r][c4] = *(const u16x4*)(BT + (size_t)(n0 + r) * 512 + k0 + c4);
    }
    __syncthreads();
#pragma unroll
    for (int kk = 0; kk < 2; ++kk) {
      bf16x8 af[2], bg[4];
#pragma unroll
      for (int i = 0; i < 2; ++i) af[i] = *(const bf16x8*)&As[wm + i * 16 + lr][kk * 32 + lg * 8];
#pragma unroll
      for (int j = 0; j < 4; ++j) bg[j] = *(const bf16x8*)&Bs[wn + j * 16 + lr][kk * 32 + lg * 8];
#pragma unroll
      for (int i = 0; i < 2; ++i)
#pragma unroll
        for (int j = 0; j < 4; ++j)
          acc[i][j] = __builtin_amdgcn_mfma_f32_16x16x32_bf16(af[i], bg[j], acc[i][j], 0, 0, 0);
    }
    __syncthreads();
  }

#pragma unroll
  for (int i = 0; i < 2; ++i)
#pragma unroll
    for (int j = 0; j < 4; ++j) {
      int mbase = m0 + wm + i * 16 + lg * 4;
      int n = n0 + wn + j * 16 + lr;
      float bvl = bias[n];
      int h = n >> 6, hd = n & 63;
      int bseg = mbase >> 10, s0 = mbase & 1023;
      if (blockIdx.z == 2) {
        u16x4 pk;
#pragma unroll
        for (int r = 0; r < 4; ++r) pk[r] = f2b(acc[i][j][r] + bvl);
        *(u16x4*)(OvT + (((size_t)(bseg * H_ + h) * 64 + hd) * 1024 + s0)) = pk;
      } else {
        unsigned short* outp = blockIdx.z == 0 ? Oq : Ok;
#pragma unroll
        for (int r = 0; r < 4; ++r) {
          float v = acc[i][j][r] + bvl;
          outp[(((size_t)bseg * H_ + h) * S_ + s0 + r) * HD_ + hd] = f2b(v);
        }
      }
    }
}

// ---------------- output projection GEMM, 64x128 tiles, BK=64: bf16 A @ W^T + bias -> fp32 ----------------
__global__ __launch_bounds__(256) void k_gemm_out(const unsigned short* A, const unsigned short* BT,
                                                  const float* bias, float* outp) {
  __shared__ unsigned short As[64][72];
  __shared__ unsigned short Bs[128][72];
  const int tid = threadIdx.x;
  const int lane = tid & 63, wave = tid >> 6;
  const int lr = lane & 15, lg = lane >> 4;
  const int wm = (wave >> 1) * 32, wn = (wave & 1) * 64;
  const int m0 = blockIdx.x * 64, n0 = blockIdx.y * 128;

  f32x4 acc[2][4];
#pragma unroll
  for (int i = 0; i < 2; ++i)
#pragma unroll
    for (int j = 0; j < 4; ++j) acc[i][j] = (f32x4){0.f, 0.f, 0.f, 0.f};

  for (int k0 = 0; k0 < 512; k0 += 64) {
#pragma unroll
    for (int i = 0; i < 4; ++i) {
      int idx = tid + i * 256;
      int r = idx >> 4, c4 = (idx & 15) * 4;
      *(u16x4*)&As[r][c4] = *(const u16x4*)(A + (size_t)(m0 + r) * 512 + k0 + c4);
    }
#pragma unroll
    for (int i = 0; i < 8; ++i) {
      int idx = tid + i * 256;
      int r = idx >> 4, c4 = (idx & 15) * 4;
      *(u16x4*)&Bs[r][c4] = *(const u16x4*)(BT + (size_t)(n0 + r) * 512 + k0 + c4);
    }
    __syncthreads();
#pragma unroll
    for (int kk = 0; kk < 2; ++kk) {
      bf16x8 af[2], bg[4];
#pragma unroll
      for (int i = 0; i < 2; ++i) af[i] = *(const bf16x8*)&As[wm + i * 16 + lr][kk * 32 + lg * 8];
#pragma unroll
      for (int j = 0; j < 4; ++j) bg[j] = *(const bf16x8*)&Bs[wn + j * 16 + lr][kk * 32 + lg * 8];
#pragma unroll
      for (int i = 0; i < 2; ++i)
#pragma unroll
        for (int j = 0; j < 4; ++j)
          acc[i][j] = __builtin_amdgcn_mfma_f32_16x16x32_bf16(af[i], bg[j], acc[i][j], 0, 0, 0);
    }
    __syncthreads();
  }

#pragma unroll
  for (int i = 0; i < 2; ++i)
#pragma unroll
    for (int j = 0; j < 4; ++j) {
      int mbase = m0 + wm + i * 16 + lg * 4;
      int n = n0 + wn + j * 16 + lr;
      float bvl = bias[n];
#pragma unroll
      for (int r = 0; r < 4; ++r)
        outp[(size_t)(mbase + r) * 512 + n] = acc[i][j][r] + bvl;
    }
}

// ---------------- fused SINGLE-PASS attention, k-split across wave pairs ----------------
// Block: 256 thr / 4 waves / 32 q-rows. Wave w: wq=w&1 -> q rows [q0+wq*16, +16);
// wk=w>>1 -> k half [wk*512, wk*512+512). Per lane: 8 tiles of P' (u16x4[8][4] = 64 VGPR).
// Partial row-sums and partial O combined through LDS (lsbuf / Obuf).
__global__ __launch_bounds__(256, 2) void k_attn(const unsigned short* Qb, const unsigned short* Kb,
                                                 const unsigned short* VT, const float* tbl,
                                                 const int* mask, float* out_attn,
                                                 unsigned short* Xp) {
  const int tid = threadIdx.x;
  const int lane = tid & 63, w = tid >> 6;
  const int lr = lane & 15, lg = lane >> 4;
  const int wq = w & 1, wk = w >> 1;
  const int bh = blockIdx.y, b = bh >> 3, h = bh & 7;
  const int q0 = blockIdx.x * 32;

  __shared__ unsigned short Ks[2][64][64];   // per k-half K tile, XOR-swizzled 16B chunks
  __shared__ unsigned short Vt[2][64][64];   // per k-half V^T tile, same swizzle
  __shared__ unsigned short Pl[4][16][64];   // per-wave P tile
  __shared__ float biasT[3969];
  __shared__ float mbig[1024];
  __shared__ float lsbuf[4][16];
  __shared__ float Obuf[2][16][68];          // +4 pad: avoid 4-way bank conflict on lg
  __shared__ int tbad[16];

  const unsigned short* Qh = Qb + (size_t)bh * (S_ * HD_);
  const unsigned short* Kh = Kb + (size_t)bh * (S_ * HD_);
  const unsigned short* Vth = VT + (size_t)bh * (HD_ * S_);

  const int srow = tid >> 3, sc = tid & 7;   // staging: 32 rows/pass, rows srow & srow+32
  const int swz = (sc ^ (srow & 7)) * 8;

  if (tid < 16) tbad[tid] = 0;
  __syncthreads();
  for (int i = tid; i < 3969; i += 256) biasT[i] = tbl[h * 3969 + i];
  {
    int4 mv = *(const int4*)(mask + b * S_ + tid * 4);
    int base = tid * 4;
    // masked sentinel -30: finite, below any real arg, exact uniform-row limit
    mbig[base] = mv.x ? 3.0e38f : -30.f;
    mbig[base + 1] = mv.y ? 3.0e38f : -30.f;
    mbig[base + 2] = mv.z ? 3.0e38f : -30.f;
    mbig[base + 3] = mv.w ? 3.0e38f : -30.f;
    if (!(mv.x && mv.y && mv.z && mv.w)) tbad[base >> 6] = 1;
  }
  // prologue: stage it=0 tiles for both k-halves (gt=0 and gt=8)
#pragma unroll
  for (int hf = 0; hf < 2; ++hf) {
    *(bf16x8*)&Ks[hf][srow][swz] = *(const bf16x8*)(Kh + (size_t)(hf * 512 + srow) * 64 + sc * 8);
    *(bf16x8*)&Ks[hf][srow + 32][swz] = *(const bf16x8*)(Kh + (size_t)(hf * 512 + srow + 32) * 64 + sc * 8);
    *(bf16x8*)&Vt[hf][srow][swz] = *(const bf16x8*)(Vth + (size_t)srow * S_ + hf * 512 + sc * 8);
    *(bf16x8*)&Vt[hf][srow + 32][swz] = *(const bf16x8*)(Vth + (size_t)(srow + 32) * S_ + hf * 512 + sc * 8);
  }

  const int qrow = q0 + wq * 16 + lr;
  const bf16x8 bq0 = *(const bf16x8*)(Qh + (size_t)qrow * 64 + lg * 8);
  const bf16x8 bq1 = *(const bf16x8*)(Qh + (size_t)qrow * 64 + 32 + lg * 8);
  const int qterm = (qrow >> 5) * 63 + (qrow & 31) + 1984;

  u16x4 preg[8][4];   // unnormalized P' bf16, this wave's k-half only (static idx, full unroll)
  f32x4 of[4];
#pragma unroll
  for (int i = 0; i < 4; ++i) of[i] = (f32x4){0.f, 0.f, 0.f, 0.f};
  float ls = 0.f;
  __syncthreads();

#pragma unroll
  for (int it = 0; it < 8; ++it) {
    // T14: issue next iteration's global loads before compute (latency hides under MFMA/exp)
    bf16x8 nk00, nk01, nk10, nk11, nv00, nv01, nv10, nv11;
    if (it < 7) {
      int t0 = (it + 1) * 64, t1 = (8 + it + 1) * 64;
      nk00 = *(const bf16x8*)(Kh + (size_t)(t0 + srow) * 64 + sc * 8);
      nk01 = *(const bf16x8*)(Kh + (size_t)(t0 + srow + 32) * 64 + sc * 8);
      nk10 = *(const bf16x8*)(Kh + (size_t)(t1 + srow) * 64 + sc * 8);
      nk11 = *(const bf16x8*)(Kh + (size_t)(t1 + srow + 32) * 64 + sc * 8);
      nv00 = *(const bf16x8*)(Vth + (size_t)srow * S_ + t0 + sc * 8);
      nv01 = *(const bf16x8*)(Vth + (size_t)(srow + 32) * S_ + t0 + sc * 8);
      nv10 = *(const bf16x8*)(Vth + (size_t)srow * S_ + t1 + sc * 8);
      nv11 = *(const bf16x8*)(Vth + (size_t)(srow + 32) * S_ + t1 + sc * 8);
    }
    const int gt = wk * 8 + it;
    const int bidx = qterm - 126 * gt;
    const bool bad = tbad[gt] != 0;
#pragma unroll
    for (int fn = 0; fn < 4; ++fn) {
      const unsigned short* krow = &Ks[wk][fn * 16 + lr][0];
      bf16x8 a0 = *(const bf16x8*)(krow + (lg ^ (lr & 7)) * 8);
      bf16x8 a1 = *(const bf16x8*)(krow + ((4 + lg) ^ (lr & 7)) * 8);
      f32x4 s = (f32x4){0.f, 0.f, 0.f, 0.f};
      s = __builtin_amdgcn_mfma_f32_16x16x32_bf16(a0, bq0, s, 0, 0, 0);
      s = __builtin_amdgcn_mfma_f32_16x16x32_bf16(a1, bq1, s, 0, 0, 0);
      const int kob = fn * 16 + lg * 4;
      const int ib = bidx - kob - (fn >= 2 ? 31 : 0);
      u16x4 pb;
#pragma unroll
      for (int r = 0; r < 4; ++r) {
        float arg = fmaf(s[r], 0.125f, biasT[ib - r]);
        if (bad) arg = fminf(arg, mbig[gt * 64 + kob + r]);
        float p = __expf(arg);       // unnormalized
        ls += p;
        pb[r] = f2b(p);
      }
      preg[it][fn] = pb;
      *(u16x4*)((char*)&Pl[w][lr][0] + ((fn * 2 + (lg >> 1)) ^ (lr & 7)) * 16 + (lg & 1) * 8) = pb;
    }
    // PV with unnormalized P' (same-wave Pl dependency; compiler inserts lgkmcnt)
#pragma unroll
    for (int c = 0; c < 2; ++c) {
      bf16x8 pa = *(const bf16x8*)((const char*)&Pl[w][lr][0] + ((c * 4 + lg) ^ (lr & 7)) * 16);
#pragma unroll
      for (int fn2 = 0; fn2 < 4; ++fn2) {
        const unsigned short* vrow = &Vt[wk][fn2 * 16 + lr][0];
        bf16x8 bv = *(const bf16x8*)((const char*)vrow + ((c * 4 + lg) ^ (lr & 7)) * 16);
        of[fn2] = __builtin_amdgcn_mfma_f32_16x16x32_bf16(pa, bv, of[fn2], 0, 0, 0);
      }
    }
    if (it < 7) {
      __syncthreads();   // all waves done reading Ks/Vt
      *(bf16x8*)&Ks[0][srow][swz] = nk00;
      *(bf16x8*)&Ks[0][srow + 32][swz] = nk01;
      *(bf16x8*)&Ks[1][srow][swz] = nk10;
      *(bf16x8*)&Ks[1][srow + 32][swz] = nk11;
      *(bf16x8*)&Vt[0][srow][swz] = nv00;
      *(bf16x8*)&Vt[0][srow + 32][swz] = nv01;
      *(bf16x8*)&Vt[1][srow][swz] = nv10;
      *(bf16x8*)&Vt[1][srow + 32][swz] = nv11;
      __syncthreads();   // writes visible
    }
  }

  // ---- combine partial sums / partial O across the two k-halves ----
  ls += __shfl_xor(ls, 16, 64);
  ls += __shfl_xor(ls, 32, 64);           // all lg copies now hold this wave's partial row-sum
  if (lg == 0) lsbuf[w][lr] = ls;
  if (wk == 1) {
#pragma unroll
    for (int fn2 = 0; fn2 < 4; ++fn2)
#pragma unroll
      for (int r = 0; r < 4; ++r) Obuf[wq][lg * 4 + r][fn2 * 16 + lr] = of[fn2][r];
  }
  __syncthreads();
  const float inv = 1.f / (lsbuf[wq][lr] + lsbuf[2 + wq][lr]);  // full-row normalizer for qrow
  f32x4 invq;
#pragma unroll
  for (int r = 0; r < 4; ++r) invq[r] = __shfl(inv, lg * 4 + r, 64);

  // ---- epilogue A: normalized attention, this wave's k-half columns ----
  float* oa = out_attn + (size_t)bh * (S_ * S_) + (size_t)qrow * S_ + wk * 512;
#pragma unroll
  for (int it = 0; it < 8; ++it) {
#pragma unroll
    for (int fn = 0; fn < 4; ++fn) {
      u16x4 pb = preg[it][fn];
      f32x4 pr;
#pragma unroll
      for (int r = 0; r < 4; ++r) pr[r] = b2f(pb[r]) * inv;
      *(f32x4*)(oa + it * 64 + fn * 16 + lg * 4) = pr;
    }
  }

  // ---- epilogue B: combine O halves, scale by per-row inv, write Xp (waves wk==0) ----
  if (wk == 0) {
#pragma unroll
    for (int fn2 = 0; fn2 < 4; ++fn2)
#pragma unroll
      for (int r = 0; r < 4; ++r) {
        int q = q0 + wq * 16 + lg * 4 + r;
        float val = (of[fn2][r] + Obuf[wq][lg * 4 + r][fn2 * 16 + lr]) * invq[r];
        Xp[((size_t)b * S_ + q) * D_ + h * 64 + fn2 * 16 + lr] = f2b(val);
      }
  }
}

// ---------------- host launch ----------------
extern "C" void kernel_launch(void* const* d_in, const int* in_sizes, int n_in,
                              void* d_out, int out_size, void* d_ws, size_t ws_size,
                              hipStream_t stream) {
  const float* query = (const float*)d_in[0];
  const float* key   = (const float*)d_in[1];
  const float* value = (const float*)d_in[2];
  const int*   maskp = (const int*)d_in[3];
  const float* Wq = (const float*)d_in[4];
  const float* bq = (const float*)d_in[5];
  const float* Wk = (const float*)d_in[6];
  const float* bk = (const float*)d_in[7];
  const float* Wv = (const float*)d_in[8];
  const float* bv = (const float*)d_in[9];
  const float* Wo = (const float*)d_in[10];
  const float* bo = (const float*)d_in[11];
  const float* W1 = (const float*)d_in[12];
  const float* b1 = (const float*)d_in[13];
  const float* W2 = (const float*)d_in[14];
  const float* b2 = (const float*)d_in[15];

  char* ws = (char*)d_ws;
  const size_t MB4 = (size_t)4 * 1024 * 1024;
  unsigned short* Qb  = (unsigned short*)(ws);
  unsigned short* Kb  = (unsigned short*)(ws + MB4);
  unsigned short* VT  = (unsigned short*)(ws + 2 * MB4);
  unsigned short* Xp  = (unsigned short*)(ws + 3 * MB4);
  unsigned short* WqT = (unsigned short*)(ws + 4 * MB4);
  unsigned short* WkT = (unsigned short*)(ws + 4 * MB4 + 524288);
  unsigned short* WvT = (unsigned short*)(ws + 4 * MB4 + 2 * 524288);
  unsigned short* WoT = (unsigned short*)(ws + 4 * MB4 + 3 * 524288);
  float* table        = (float*)(ws + 4 * MB4 + 4 * 524288);

  float* out_x = (float*)d_out;
  float* out_attn = out_x + (size_t)B_ * S_ * D_;

  k_prep<<<dim3(16, 16, 5), 256, 0, stream>>>(Wq, Wk, Wv, Wo, WqT, WkT, WvT, WoT,
                                              W1, b1, W2, b2, table);
  k_gemm_qkv<<<dim3(64, 4, 3), 256, 0, stream>>>(query, key, value, WqT, WkT, WvT,
                                                 bq, bk, bv, Qb, Kb, VT);
  k_attn<<<dim3(32, 32), 256, 0, stream>>>(Qb, Kb, VT, table, maskp, out_attn, Xp);
  k_gemm_out<<<dim3(64, 4), 256, 0, stream>>>(Xp, WoT, bo, out_x);
}

// Round 8
// 142.021 us; speedup vs baseline: 1.7275x; 1.0139x over previous
//
#include <hip/hip_runtime.h>
#include <hip/hip_bf16.h>

typedef __attribute__((ext_vector_type(4))) float f32x4;
typedef __attribute__((ext_vector_type(8))) short bf16x8;
typedef __attribute__((ext_vector_type(4))) unsigned short u16x4;

#define DEVI __device__ __forceinline__

constexpr int B_ = 4, S_ = 1024, D_ = 512, H_ = 8, HD_ = 64;
constexpr float CSH = 11.0903548f;  // fixed softmax shift (folded into bias table)

DEVI unsigned short f2b(float f) {
  union { float f; unsigned u; } v; v.f = f;
  unsigned r = v.u + 0x7fffu + ((v.u >> 16) & 1u);
  return (unsigned short)(r >> 16);
}

DEVI float b2f(unsigned short u) {
  union { unsigned u; float f; } v; v.u = ((unsigned)u) << 16;
  return v.f;
}

// ---------------- prep: weight transpose+bf16 (z=0..3) and bias MLP table (z=4) ----------------
__global__ __launch_bounds__(256) void k_prep(const float* Wa, const float* Wb,
                                              const float* Wc, const float* Wd,
                                              unsigned short* T0, unsigned short* T1,
                                              unsigned short* T2, unsigned short* T3,
                                              const float* mW1, const float* mb1,
                                              const float* mW2, const float* mb2,
                                              float* table) {
  if (blockIdx.z == 4) {
    if (blockIdx.y != 0) return;
    int idx = blockIdx.x * 256 + threadIdx.x;
    if (idx >= 63 * 63) return;
    int dy = idx / 63 - 31, dx = idx % 63 - 31;
    float r0 = copysignf(log1pf(fabsf((float)dy)), (float)dy);
    float r1 = copysignf(log1pf(fabsf((float)dx)), (float)dx);
    float acc[8];
#pragma unroll
    for (int h = 0; h < 8; ++h) acc[h] = mb2[h];
    for (int j = 0; j < 128; ++j) {
      float hv = fmaxf(r0 * mW1[j] + r1 * mW1[128 + j] + mb1[j], 0.f);
#pragma unroll
      for (int h = 0; h < 8; ++h) acc[h] += hv * mW2[j * 8 + h];
    }
#pragma unroll
    for (int h = 0; h < 8; ++h) table[h * 3969 + idx] = acc[h] - CSH;  // shift folded in
    return;
  }
  const float* W = blockIdx.z == 0 ? Wa : blockIdx.z == 1 ? Wb : blockIdx.z == 2 ? Wc : Wd;
  unsigned short* T = blockIdx.z == 0 ? T0 : blockIdx.z == 1 ? T1 : blockIdx.z == 2 ? T2 : T3;
  __shared__ float tile[32][33];
  int tx = threadIdx.x & 31, ty = threadIdx.x >> 5;
  int n0 = blockIdx.x * 32, k0 = blockIdx.y * 32;
#pragma unroll
  for (int r = 0; r < 4; ++r) tile[ty + r * 8][tx] = W[(size_t)(k0 + ty + r * 8) * D_ + n0 + tx];
  __syncthreads();
#pragma unroll
  for (int r = 0; r < 4; ++r) T[(size_t)(n0 + ty + r * 8) * D_ + k0 + tx] = f2b(tile[tx][ty + r * 8]);
}

// ---------------- merged QKV GEMM, 64x128 tiles, BK=64; V written pre-transposed ----------------
__global__ __launch_bounds__(256) void k_gemm_qkv(const float* Aq, const float* Ak, const float* Av,
                                                  const unsigned short* Tq, const unsigned short* Tk,
                                                  const unsigned short* Tv,
                                                  const float* bqv, const float* bkv, const float* bvv,
                                                  unsigned short* Oq, unsigned short* Ok,
                                                  unsigned short* OvT) {
  const float* A = blockIdx.z == 0 ? Aq : blockIdx.z == 1 ? Ak : Av;
  const unsigned short* BT = blockIdx.z == 0 ? Tq : blockIdx.z == 1 ? Tk : Tv;
  const float* bias = blockIdx.z == 0 ? bqv : blockIdx.z == 1 ? bkv : bvv;

  __shared__ unsigned short As[64][72];   // +8 pad: 144B row stride
  __shared__ unsigned short Bs[128][72];
  const int tid = threadIdx.x;
  const int lane = tid & 63, wave = tid >> 6;
  const int lr = lane & 15, lg = lane >> 4;
  const int wm = (wave >> 1) * 32, wn = (wave & 1) * 64;
  const int m0 = blockIdx.x * 64, n0 = blockIdx.y * 128;

  f32x4 acc[2][4];
#pragma unroll
  for (int i = 0; i < 2; ++i)
#pragma unroll
    for (int j = 0; j < 4; ++j) acc[i][j] = (f32x4){0.f, 0.f, 0.f, 0.f};

  for (int k0 = 0; k0 < 512; k0 += 64) {
#pragma unroll
    for (int i = 0; i < 4; ++i) {   // A: 64 rows x 16 float4 chunks = 1024 tasks
      int idx = tid + i * 256;
      int r = idx >> 4, c4 = (idx & 15) * 4;
      float4 fv = *(const float4*)(A + (size_t)(m0 + r) * 512 + k0 + c4);
      u16x4 wv;
      wv[0] = f2b(fv.x); wv[1] = f2b(fv.y); wv[2] = f2b(fv.z); wv[3] = f2b(fv.w);
      *(u16x4*)&As[r][c4] = wv;
    }
#pragma unroll
    for (int i = 0; i < 8; ++i) {   // B: 128 rows x 16 u16x4 chunks = 2048 tasks
      int idx = tid + i * 256;
      int r = idx >> 4, c4 = (idx & 15) * 4;
      *(u16x4*)&Bs[r][c4] = *(const u16x4*)(BT + (size_t)(n0 + r) * 512 + k0 + c4);
    }
    __syncthreads();
#pragma unroll
    for (int kk = 0; kk < 2; ++kk) {
      bf16x8 af[2], bg[4];
#pragma unroll
      for (int i = 0; i < 2; ++i) af[i] = *(const bf16x8*)&As[wm + i * 16 + lr][kk * 32 + lg * 8];
#pragma unroll
      for (int j = 0; j < 4; ++j) bg[j] = *(const bf16x8*)&Bs[wn + j * 16 + lr][kk * 32 + lg * 8];
#pragma unroll
      for (int i = 0; i < 2; ++i)
#pragma unroll
        for (int j = 0; j < 4; ++j)
          acc[i][j] = __builtin_amdgcn_mfma_f32_16x16x32_bf16(af[i], bg[j], acc[i][j], 0, 0, 0);
    }
    __syncthreads();
  }

#pragma unroll
  for (int i = 0; i < 2; ++i)
#pragma unroll
    for (int j = 0; j < 4; ++j) {
      int mbase = m0 + wm + i * 16 + lg * 4;
      int n = n0 + wn + j * 16 + lr;
      float bvl = bias[n];
      int h = n >> 6, hd = n & 63;
      int bseg = mbase >> 10, s0 = mbase & 1023;
      if (blockIdx.z == 2) {
        u16x4 pk;
#pragma unroll
        for (int r = 0; r < 4; ++r) pk[r] = f2b(acc[i][j][r] + bvl);
        *(u16x4*)(OvT + (((size_t)(bseg * H_ + h) * 64 + hd) * 1024 + s0)) = pk;
      } else {
        unsigned short* outp = blockIdx.z == 0 ? Oq : Ok;
#pragma unroll
        for (int r = 0; r < 4; ++r) {
          float v = acc[i][j][r] + bvl;
          outp[(((size_t)bseg * H_ + h) * S_ + s0 + r) * HD_ + hd] = f2b(v);
        }
      }
    }
}

// ---------------- output projection GEMM, 64x128 tiles, BK=64: bf16 A @ W^T + bias -> fp32 ----------------
__global__ __launch_bounds__(256) void k_gemm_out(const unsigned short* A, const unsigned short* BT,
                                                  const float* bias, float* outp) {
  __shared__ unsigned short As[64][72];
  __shared__ unsigned short Bs[128][72];
  const int tid = threadIdx.x;
  const int lane = tid & 63, wave = tid >> 6;
  const int lr = lane & 15, lg = lane >> 4;
  const int wm = (wave >> 1) * 32, wn = (wave & 1) * 64;
  const int m0 = blockIdx.x * 64, n0 = blockIdx.y * 128;

  f32x4 acc[2][4];
#pragma unroll
  for (int i = 0; i < 2; ++i)
#pragma unroll
    for (int j = 0; j < 4; ++j) acc[i][j] = (f32x4){0.f, 0.f, 0.f, 0.f};

  for (int k0 = 0; k0 < 512; k0 += 64) {
#pragma unroll
    for (int i = 0; i < 4; ++i) {
      int idx = tid + i * 256;
      int r = idx >> 4, c4 = (idx & 15) * 4;
      *(u16x4*)&As[r][c4] = *(const u16x4*)(A + (size_t)(m0 + r) * 512 + k0 + c4);
    }
#pragma unroll
    for (int i = 0; i < 8; ++i) {
      int idx = tid + i * 256;
      int r = idx >> 4, c4 = (idx & 15) * 4;
      *(u16x4*)&Bs[r][c4] = *(const u16x4*)(BT + (size_t)(n0 + r) * 512 + k0 + c4);
    }
    __syncthreads();
#pragma unroll
    for (int kk = 0; kk < 2; ++kk) {
      bf16x8 af[2], bg[4];
#pragma unroll
      for (int i = 0; i < 2; ++i) af[i] = *(const bf16x8*)&As[wm + i * 16 + lr][kk * 32 + lg * 8];
#pragma unroll
      for (int j = 0; j < 4; ++j) bg[j] = *(const bf16x8*)&Bs[wn + j * 16 + lr][kk * 32 + lg * 8];
#pragma unroll
      for (int i = 0; i < 2; ++i)
#pragma unroll
        for (int j = 0; j < 4; ++j)
          acc[i][j] = __builtin_amdgcn_mfma_f32_16x16x32_bf16(af[i], bg[j], acc[i][j], 0, 0, 0);
    }
    __syncthreads();
  }

#pragma unroll
  for (int i = 0; i < 2; ++i)
#pragma unroll
    for (int j = 0; j < 4; ++j) {
      int mbase = m0 + wm + i * 16 + lg * 4;
      int n = n0 + wn + j * 16 + lr;
      float bvl = bias[n];
#pragma unroll
      for (int r = 0; r < 4; ++r)
        outp[(size_t)(mbase + r) * 512 + n] = acc[i][j][r] + bvl;
    }
}

// ---------------- fused SINGLE-PASS attention, k-split across wave pairs ----------------
// Block: 256 thr / 4 waves / 32 q-rows. Wave w: wq=w&1 -> q rows [q0+wq*16, +16);
// wk=w>>1 -> k half [wk*512, +512). Per lane: 8 tiles of P' (u16x4[8][4] = 32 VGPR).
// Staging is BETWEEN barriers after compute (transient regs only — no live prefetch
// across compute; the co-resident 2nd block hides the load latency). Partial row-sums
// and partial O combined through LDS (lsbuf / Obuf).
__global__ __launch_bounds__(256, 2) void k_attn(const unsigned short* Qb, const unsigned short* Kb,
                                                 const unsigned short* VT, const float* tbl,
                                                 const int* mask, float* out_attn,
                                                 unsigned short* Xp) {
  const int tid = threadIdx.x;
  const int lane = tid & 63, w = tid >> 6;
  const int lr = lane & 15, lg = lane >> 4;
  const int wq = w & 1, wk = w >> 1;
  const int bh = blockIdx.y, b = bh >> 3, h = bh & 7;
  const int q0 = blockIdx.x * 32;

  __shared__ unsigned short Ks[2][64][64];   // per k-half K tile, XOR-swizzled 16B chunks
  __shared__ unsigned short Vt[2][64][64];   // per k-half V^T tile, same swizzle
  __shared__ unsigned short Pl[4][16][64];   // per-wave P tile
  __shared__ float biasT[3969];
  __shared__ float mbig[1024];
  __shared__ float lsbuf[4][16];
  __shared__ float Obuf[2][16][68];          // +4 pad
  __shared__ int tbad[16];

  const unsigned short* Qh = Qb + (size_t)bh * (S_ * HD_);
  const unsigned short* Kh = Kb + (size_t)bh * (S_ * HD_);
  const unsigned short* Vth = VT + (size_t)bh * (HD_ * S_);

  const int srow = tid >> 3, sc = tid & 7;   // staging: 32 rows/pass, rows srow & srow+32
  const int swz = (sc ^ (srow & 7)) * 8;

  if (tid < 16) tbad[tid] = 0;
  __syncthreads();
  for (int i = tid; i < 3969; i += 256) biasT[i] = tbl[h * 3969 + i];
  {
    int4 mv = *(const int4*)(mask + b * S_ + tid * 4);
    int base = tid * 4;
    // masked sentinel -30: finite, below any real arg, exact uniform-row limit
    mbig[base] = mv.x ? 3.0e38f : -30.f;
    mbig[base + 1] = mv.y ? 3.0e38f : -30.f;
    mbig[base + 2] = mv.z ? 3.0e38f : -30.f;
    mbig[base + 3] = mv.w ? 3.0e38f : -30.f;
    if (!(mv.x && mv.y && mv.z && mv.w)) tbad[base >> 6] = 1;
  }
  // prologue: stage it=0 tiles for both k-halves
#pragma unroll
  for (int hf = 0; hf < 2; ++hf) {
    *(bf16x8*)&Ks[hf][srow][swz] = *(const bf16x8*)(Kh + (size_t)(hf * 512 + srow) * 64 + sc * 8);
    *(bf16x8*)&Ks[hf][srow + 32][swz] = *(const bf16x8*)(Kh + (size_t)(hf * 512 + srow + 32) * 64 + sc * 8);
    *(bf16x8*)&Vt[hf][srow][swz] = *(const bf16x8*)(Vth + (size_t)srow * S_ + hf * 512 + sc * 8);
    *(bf16x8*)&Vt[hf][srow + 32][swz] = *(const bf16x8*)(Vth + (size_t)(srow + 32) * S_ + hf * 512 + sc * 8);
  }

  const int qrow = q0 + wq * 16 + lr;
  const bf16x8 bq0 = *(const bf16x8*)(Qh + (size_t)qrow * 64 + lg * 8);
  const bf16x8 bq1 = *(const bf16x8*)(Qh + (size_t)qrow * 64 + 32 + lg * 8);
  const int qterm = (qrow >> 5) * 63 + (qrow & 31) + 1984;

  u16x4 preg[8][4];   // unnormalized P' bf16, this wave's k-half (static idx, full unroll)
  f32x4 of[4];
#pragma unroll
  for (int i = 0; i < 4; ++i) of[i] = (f32x4){0.f, 0.f, 0.f, 0.f};
  float ls = 0.f;
  __syncthreads();

#pragma unroll
  for (int it = 0; it < 8; ++it) {
    const int gt = wk * 8 + it;
    const int bidx = qterm - 126 * gt;
    const bool bad = tbad[gt] != 0;
#pragma unroll
    for (int fn = 0; fn < 4; ++fn) {
      const unsigned short* krow = &Ks[wk][fn * 16 + lr][0];
      bf16x8 a0 = *(const bf16x8*)(krow + (lg ^ (lr & 7)) * 8);
      bf16x8 a1 = *(const bf16x8*)(krow + ((4 + lg) ^ (lr & 7)) * 8);
      f32x4 s = (f32x4){0.f, 0.f, 0.f, 0.f};
      s = __builtin_amdgcn_mfma_f32_16x16x32_bf16(a0, bq0, s, 0, 0, 0);
      s = __builtin_amdgcn_mfma_f32_16x16x32_bf16(a1, bq1, s, 0, 0, 0);
      const int kob = fn * 16 + lg * 4;
      const int ib = bidx - kob - (fn >= 2 ? 31 : 0);
      u16x4 pb;
#pragma unroll
      for (int r = 0; r < 4; ++r) {
        float arg = fmaf(s[r], 0.125f, biasT[ib - r]);
        if (bad) arg = fminf(arg, mbig[gt * 64 + kob + r]);
        float p = __expf(arg);       // unnormalized
        ls += p;
        pb[r] = f2b(p);
      }
      preg[it][fn] = pb;
      *(u16x4*)((char*)&Pl[w][lr][0] + ((fn * 2 + (lg >> 1)) ^ (lr & 7)) * 16 + (lg & 1) * 8) = pb;
    }
    // PV with unnormalized P' (same-wave Pl dependency; compiler inserts lgkmcnt)
#pragma unroll
    for (int c = 0; c < 2; ++c) {
      bf16x8 pa = *(const bf16x8*)((const char*)&Pl[w][lr][0] + ((c * 4 + lg) ^ (lr & 7)) * 16);
#pragma unroll
      for (int fn2 = 0; fn2 < 4; ++fn2) {
        const unsigned short* vrow = &Vt[wk][fn2 * 16 + lr][0];
        bf16x8 bv = *(const bf16x8*)((const char*)vrow + ((c * 4 + lg) ^ (lr & 7)) * 16);
        of[fn2] = __builtin_amdgcn_mfma_f32_16x16x32_bf16(pa, bv, of[fn2], 0, 0, 0);
      }
    }
    if (it < 7) {
      __syncthreads();   // all waves done reading Ks/Vt
      // staging between barriers: loads cannot be hoisted across __syncthreads,
      // so these registers are transient (no pressure during compute)
      const int t0 = (it + 1) * 64, t1 = (8 + it + 1) * 64;
      *(bf16x8*)&Ks[0][srow][swz] = *(const bf16x8*)(Kh + (size_t)(t0 + srow) * 64 + sc * 8);
      *(bf16x8*)&Ks[0][srow + 32][swz] = *(const bf16x8*)(Kh + (size_t)(t0 + srow + 32) * 64 + sc * 8);
      *(bf16x8*)&Ks[1][srow][swz] = *(const bf16x8*)(Kh + (size_t)(t1 + srow) * 64 + sc * 8);
      *(bf16x8*)&Ks[1][srow + 32][swz] = *(const bf16x8*)(Kh + (size_t)(t1 + srow + 32) * 64 + sc * 8);
      *(bf16x8*)&Vt[0][srow][swz] = *(const bf16x8*)(Vth + (size_t)srow * S_ + t0 + sc * 8);
      *(bf16x8*)&Vt[0][srow + 32][swz] = *(const bf16x8*)(Vth + (size_t)(srow + 32) * S_ + t0 + sc * 8);
      *(bf16x8*)&Vt[1][srow][swz] = *(const bf16x8*)(Vth + (size_t)srow * S_ + t1 + sc * 8);
      *(bf16x8*)&Vt[1][srow + 32][swz] = *(const bf16x8*)(Vth + (size_t)(srow + 32) * S_ + t1 + sc * 8);
      __syncthreads();   // writes visible
    }
  }

  // ---- combine partial sums / partial O across the two k-halves ----
  ls += __shfl_xor(ls, 16, 64);
  ls += __shfl_xor(ls, 32, 64);           // all lg copies hold this wave's partial row-sum
  if (lg == 0) lsbuf[w][lr] = ls;
  if (wk == 1) {
#pragma unroll
    for (int fn2 = 0; fn2 < 4; ++fn2)
#pragma unroll
      for (int r = 0; r < 4; ++r) Obuf[wq][lg * 4 + r][fn2 * 16 + lr] = of[fn2][r];
  }
  __syncthreads();
  const float inv = 1.f / (lsbuf[wq][lr] + lsbuf[2 + wq][lr]);  // full-row normalizer for qrow
  f32x4 invq;
#pragma unroll
  for (int r = 0; r < 4; ++r) invq[r] = __shfl(inv, lg * 4 + r, 64);

  // ---- epilogue A: normalized attention, this wave's k-half columns ----
  float* oa = out_attn + (size_t)bh * (S_ * S_) + (size_t)qrow * S_ + wk * 512;
#pragma unroll
  for (int it = 0; it < 8; ++it) {
#pragma unroll
    for (int fn = 0; fn < 4; ++fn) {
      u16x4 pb = preg[it][fn];
      f32x4 pr;
#pragma unroll
      for (int r = 0; r < 4; ++r) pr[r] = b2f(pb[r]) * inv;
      *(f32x4*)(oa + it * 64 + fn * 16 + lg * 4) = pr;
    }
  }

  // ---- epilogue B: combine O halves, scale by per-row inv, write Xp (waves wk==0) ----
  if (wk == 0) {
#pragma unroll
    for (int fn2 = 0; fn2 < 4; ++fn2)
#pragma unroll
      for (int r = 0; r < 4; ++r) {
        int q = q0 + wq * 16 + lg * 4 + r;
        float val = (of[fn2][r] + Obuf[wq][lg * 4 + r][fn2 * 16 + lr]) * invq[r];
        Xp[((size_t)b * S_ + q) * D_ + h * 64 + fn2 * 16 + lr] = f2b(val);
      }
  }
}

// ---------------- host launch ----------------
extern "C" void kernel_launch(void* const* d_in, const int* in_sizes, int n_in,
                              void* d_out, int out_size, void* d_ws, size_t ws_size,
                              hipStream_t stream) {
  const float* query = (const float*)d_in[0];
  const float* key   = (const float*)d_in[1];
  const float* value = (const float*)d_in[2];
  const int*   maskp = (const int*)d_in[3];
  const float* Wq = (const float*)d_in[4];
  const float* bq = (const float*)d_in[5];
  const float* Wk = (const float*)d_in[6];
  const float* bk = (const float*)d_in[7];
  const float* Wv = (const float*)d_in[8];
  const float* bv = (const float*)d_in[9];
  const float* Wo = (const float*)d_in[10];
  const float* bo = (const float*)d_in[11];
  const float* W1 = (const float*)d_in[12];
  const float* b1 = (const float*)d_in[13];
  const float* W2 = (const float*)d_in[14];
  const float* b2 = (const float*)d_in[15];

  char* ws = (char*)d_ws;
  const size_t MB4 = (size_t)4 * 1024 * 1024;
  unsigned short* Qb  = (unsigned short*)(ws);
  unsigned short* Kb  = (unsigned short*)(ws + MB4);
  unsigned short* VT  = (unsigned short*)(ws + 2 * MB4);
  unsigned short* Xp  = (unsigned short*)(ws + 3 * MB4);
  unsigned short* WqT = (unsigned short*)(ws + 4 * MB4);
  unsigned short* WkT = (unsigned short*)(ws + 4 * MB4 + 524288);
  unsigned short* WvT = (unsigned short*)(ws + 4 * MB4 + 2 * 524288);
  unsigned short* WoT = (unsigned short*)(ws + 4 * MB4 + 3 * 524288);
  float* table        = (float*)(ws + 4 * MB4 + 4 * 524288);

  float* out_x = (float*)d_out;
  float* out_attn = out_x + (size_t)B_ * S_ * D_;

  k_prep<<<dim3(16, 16, 5), 256, 0, stream>>>(Wq, Wk, Wv, Wo, WqT, WkT, WvT, WoT,
                                              W1, b1, W2, b2, table);
  k_gemm_qkv<<<dim3(64, 4, 3), 256, 0, stream>>>(query, key, value, WqT, WkT, WvT,
                                                 bq, bk, bv, Qb, Kb, VT);
  k_attn<<<dim3(32, 32), 256, 0, stream>>>(Qb, Kb, VT, table, maskp, out_attn, Xp);
  k_gemm_out<<<dim3(64, 4), 256, 0, stream>>>(Xp, WoT, bo, out_x);
}

// Round 9
// 108.481 us; speedup vs baseline: 2.2617x; 1.3092x over previous
//
#include <hip/hip_runtime.h>
#include <hip/hip_bf16.h>

typedef __attribute__((ext_vector_type(4))) float f32x4;
typedef __attribute__((ext_vector_type(8))) short bf16x8;
typedef __attribute__((ext_vector_type(4))) unsigned short u16x4;

#define DEVI __device__ __forceinline__

constexpr int B_ = 4, S_ = 1024, D_ = 512, H_ = 8, HD_ = 64;
constexpr float CSH = 11.0903548f;  // fixed softmax shift (folded into bias table)

DEVI unsigned short f2b(float f) {
  union { float f; unsigned u; } v; v.f = f;
  unsigned r = v.u + 0x7fffu + ((v.u >> 16) & 1u);
  return (unsigned short)(r >> 16);
}

DEVI float b2f(unsigned short u) {
  union { unsigned u; float f; } v; v.u = ((unsigned)u) << 16;
  return v.f;
}

// ---------------- prep: weight transpose+bf16 (z=0..3) and bias MLP table (z=4) ----------------
__global__ __launch_bounds__(256) void k_prep(const float* Wa, const float* Wb,
                                              const float* Wc, const float* Wd,
                                              unsigned short* T0, unsigned short* T1,
                                              unsigned short* T2, unsigned short* T3,
                                              const float* mW1, const float* mb1,
                                              const float* mW2, const float* mb2,
                                              float* table) {
  if (blockIdx.z == 4) {
    if (blockIdx.y != 0) return;
    int idx = blockIdx.x * 256 + threadIdx.x;
    if (idx >= 63 * 63) return;
    int dy = idx / 63 - 31, dx = idx % 63 - 31;
    float r0 = copysignf(log1pf(fabsf((float)dy)), (float)dy);
    float r1 = copysignf(log1pf(fabsf((float)dx)), (float)dx);
    float acc[8];
#pragma unroll
    for (int h = 0; h < 8; ++h) acc[h] = mb2[h];
    for (int j = 0; j < 128; ++j) {
      float hv = fmaxf(r0 * mW1[j] + r1 * mW1[128 + j] + mb1[j], 0.f);
#pragma unroll
      for (int h = 0; h < 8; ++h) acc[h] += hv * mW2[j * 8 + h];
    }
#pragma unroll
    for (int h = 0; h < 8; ++h) table[h * 3969 + idx] = acc[h] - CSH;  // shift folded in
    return;
  }
  const float* W = blockIdx.z == 0 ? Wa : blockIdx.z == 1 ? Wb : blockIdx.z == 2 ? Wc : Wd;
  unsigned short* T = blockIdx.z == 0 ? T0 : blockIdx.z == 1 ? T1 : blockIdx.z == 2 ? T2 : T3;
  __shared__ float tile[32][33];
  int tx = threadIdx.x & 31, ty = threadIdx.x >> 5;
  int n0 = blockIdx.x * 32, k0 = blockIdx.y * 32;
#pragma unroll
  for (int r = 0; r < 4; ++r) tile[ty + r * 8][tx] = W[(size_t)(k0 + ty + r * 8) * D_ + n0 + tx];
  __syncthreads();
#pragma unroll
  for (int r = 0; r < 4; ++r) T[(size_t)(n0 + ty + r * 8) * D_ + k0 + tx] = f2b(tile[tx][ty + r * 8]);
}

// ---------------- merged QKV GEMM, 64x128 tiles, BK=64; V written pre-transposed ----------------
__global__ __launch_bounds__(256) void k_gemm_qkv(const float* Aq, const float* Ak, const float* Av,
                                                  const unsigned short* Tq, const unsigned short* Tk,
                                                  const unsigned short* Tv,
                                                  const float* bqv, const float* bkv, const float* bvv,
                                                  unsigned short* Oq, unsigned short* Ok,
                                                  unsigned short* OvT) {
  const float* A = blockIdx.z == 0 ? Aq : blockIdx.z == 1 ? Ak : Av;
  const unsigned short* BT = blockIdx.z == 0 ? Tq : blockIdx.z == 1 ? Tk : Tv;
  const float* bias = blockIdx.z == 0 ? bqv : blockIdx.z == 1 ? bkv : bvv;

  __shared__ unsigned short As[64][72];   // +8 pad: 144B row stride
  __shared__ unsigned short Bs[128][72];
  const int tid = threadIdx.x;
  const int lane = tid & 63, wave = tid >> 6;
  const int lr = lane & 15, lg = lane >> 4;
  const int wm = (wave >> 1) * 32, wn = (wave & 1) * 64;
  const int m0 = blockIdx.x * 64, n0 = blockIdx.y * 128;

  f32x4 acc[2][4];
#pragma unroll
  for (int i = 0; i < 2; ++i)
#pragma unroll
    for (int j = 0; j < 4; ++j) acc[i][j] = (f32x4){0.f, 0.f, 0.f, 0.f};

  for (int k0 = 0; k0 < 512; k0 += 64) {
#pragma unroll
    for (int i = 0; i < 4; ++i) {   // A: 64 rows x 16 float4 chunks
      int idx = tid + i * 256;
      int r = idx >> 4, c4 = (idx & 15) * 4;
      float4 fv = *(const float4*)(A + (size_t)(m0 + r) * 512 + k0 + c4);
      u16x4 wv;
      wv[0] = f2b(fv.x); wv[1] = f2b(fv.y); wv[2] = f2b(fv.z); wv[3] = f2b(fv.w);
      *(u16x4*)&As[r][c4] = wv;
    }
#pragma unroll
    for (int i = 0; i < 8; ++i) {   // B: 128 rows x 16 u16x4 chunks
      int idx = tid + i * 256;
      int r = idx >> 4, c4 = (idx & 15) * 4;
      *(u16x4*)&Bs[r][c4] = *(const u16x4*)(BT + (size_t)(n0 + r) * 512 + k0 + c4);
    }
    __syncthreads();
#pragma unroll
    for (int kk = 0; kk < 2; ++kk) {
      bf16x8 af[2], bg[4];
#pragma unroll
      for (int i = 0; i < 2; ++i) af[i] = *(const bf16x8*)&As[wm + i * 16 + lr][kk * 32 + lg * 8];
#pragma unroll
      for (int j = 0; j < 4; ++j) bg[j] = *(const bf16x8*)&Bs[wn + j * 16 + lr][kk * 32 + lg * 8];
#pragma unroll
      for (int i = 0; i < 2; ++i)
#pragma unroll
        for (int j = 0; j < 4; ++j)
          acc[i][j] = __builtin_amdgcn_mfma_f32_16x16x32_bf16(af[i], bg[j], acc[i][j], 0, 0, 0);
    }
    __syncthreads();
  }

#pragma unroll
  for (int i = 0; i < 2; ++i)
#pragma unroll
    for (int j = 0; j < 4; ++j) {
      int mbase = m0 + wm + i * 16 + lg * 4;
      int n = n0 + wn + j * 16 + lr;
      float bvl = bias[n];
      int h = n >> 6, hd = n & 63;
      int bseg = mbase >> 10, s0 = mbase & 1023;
      if (blockIdx.z == 2) {
        u16x4 pk;
#pragma unroll
        for (int r = 0; r < 4; ++r) pk[r] = f2b(acc[i][j][r] + bvl);
        *(u16x4*)(OvT + (((size_t)(bseg * H_ + h) * 64 + hd) * 1024 + s0)) = pk;
      } else {
        unsigned short* outp = blockIdx.z == 0 ? Oq : Ok;
#pragma unroll
        for (int r = 0; r < 4; ++r) {
          float v = acc[i][j][r] + bvl;
          outp[(((size_t)bseg * H_ + h) * S_ + s0 + r) * HD_ + hd] = f2b(v);
        }
      }
    }
}

// ---------------- output projection GEMM, 64x128 tiles, BK=64: bf16 A @ W^T + bias -> fp32 ----------------
__global__ __launch_bounds__(256) void k_gemm_out(const unsigned short* A, const unsigned short* BT,
                                                  const float* bias, float* outp) {
  __shared__ unsigned short As[64][72];
  __shared__ unsigned short Bs[128][72];
  const int tid = threadIdx.x;
  const int lane = tid & 63, wave = tid >> 6;
  const int lr = lane & 15, lg = lane >> 4;
  const int wm = (wave >> 1) * 32, wn = (wave & 1) * 64;
  const int m0 = blockIdx.x * 64, n0 = blockIdx.y * 128;

  f32x4 acc[2][4];
#pragma unroll
  for (int i = 0; i < 2; ++i)
#pragma unroll
    for (int j = 0; j < 4; ++j) acc[i][j] = (f32x4){0.f, 0.f, 0.f, 0.f};

  for (int k0 = 0; k0 < 512; k0 += 64) {
#pragma unroll
    for (int i = 0; i < 4; ++i) {
      int idx = tid + i * 256;
      int r = idx >> 4, c4 = (idx & 15) * 4;
      *(u16x4*)&As[r][c4] = *(const u16x4*)(A + (size_t)(m0 + r) * 512 + k0 + c4);
    }
#pragma unroll
    for (int i = 0; i < 8; ++i) {
      int idx = tid + i * 256;
      int r = idx >> 4, c4 = (idx & 15) * 4;
      *(u16x4*)&Bs[r][c4] = *(const u16x4*)(BT + (size_t)(n0 + r) * 512 + k0 + c4);
    }
    __syncthreads();
#pragma unroll
    for (int kk = 0; kk < 2; ++kk) {
      bf16x8 af[2], bg[4];
#pragma unroll
      for (int i = 0; i < 2; ++i) af[i] = *(const bf16x8*)&As[wm + i * 16 + lr][kk * 32 + lg * 8];
#pragma unroll
      for (int j = 0; j < 4; ++j) bg[j] = *(const bf16x8*)&Bs[wn + j * 16 + lr][kk * 32 + lg * 8];
#pragma unroll
      for (int i = 0; i < 2; ++i)
#pragma unroll
        for (int j = 0; j < 4; ++j)
          acc[i][j] = __builtin_amdgcn_mfma_f32_16x16x32_bf16(af[i], bg[j], acc[i][j], 0, 0, 0);
    }
    __syncthreads();
  }

#pragma unroll
  for (int i = 0; i < 2; ++i)
#pragma unroll
    for (int j = 0; j < 4; ++j) {
      int mbase = m0 + wm + i * 16 + lg * 4;
      int n = n0 + wn + j * 16 + lr;
      float bvl = bias[n];
#pragma unroll
      for (int r = 0; r < 4; ++r)
        outp[(size_t)(mbase + r) * 512 + n] = acc[i][j][r] + bvl;
    }
}

// ---------------- fused single-pass attention: P' in LDS ----------------
// Block: 256 thr / 4 waves / 16 q-rows. Phase 1: wave w owns k-quarter [w*256,+256),
// stages K tiles wave-privately (KV[w]), computes QK^T -> exp -> P' into Pb + partial ls.
// One barrier. Phase 2: normalized attention stores from Pb; PV with waves split by
// d-slice (wave w -> d in [w*16,+16)) staging V^T tiles wave-privately into KV[w].
// P' never lives in registers -> no spill (the r6-r8 failure mode).
__global__ __launch_bounds__(256, 2) void k_attn(const unsigned short* Qb, const unsigned short* Kb,
                                                 const unsigned short* VT, const float* tbl,
                                                 const int* mask, float* out_attn,
                                                 unsigned short* Xp) {
  const int tid = threadIdx.x;
  const int lane = tid & 63, w = tid >> 6;
  const int lr = lane & 15, lg = lane >> 4;
  const int bh = blockIdx.y, b = bh >> 3, h = bh & 7;
  const int q0 = blockIdx.x * 16;

  __shared__ unsigned short Pb[16][1024];   // P' bf16; 8B-slot XOR swizzle by (q&7)<<1
  __shared__ unsigned short KV[4][64][64];  // wave-private: K tiles (ph1) / V^T tiles (ph2)
  __shared__ float biasS[2016];             // bias slice: rows 31-ki, 63 dx cols
  __shared__ float mbig[1024];
  __shared__ float lsbuf[4][16];
  __shared__ int tbad[16];

  const unsigned short* Qh = Qb + (size_t)bh * (S_ * HD_);
  const unsigned short* Kh = Kb + (size_t)bh * (S_ * HD_);
  const unsigned short* Vth = VT + (size_t)bh * (HD_ * S_);

  if (tid < 16) tbad[tid] = 0;
  __syncthreads();
  // bias slice: 2016 contiguous floats starting at row dy=qi (qi = q0>>5 constant per block)
  {
    const float* tsl = tbl + h * 3969 + (q0 >> 5) * 63;
    for (int i = tid; i < 2016; i += 256) biasS[i] = tsl[i];
  }
  {
    int4 mv = *(const int4*)(mask + b * S_ + tid * 4);
    int base = tid * 4;
    mbig[base] = mv.x ? 3.0e38f : -30.f;
    mbig[base + 1] = mv.y ? 3.0e38f : -30.f;
    mbig[base + 2] = mv.z ? 3.0e38f : -30.f;
    mbig[base + 3] = mv.w ? 3.0e38f : -30.f;
    if (!(mv.x && mv.y && mv.z && mv.w)) tbad[base >> 6] = 1;
  }

  const int qrow = q0 + lr;                        // all 4 waves share the 16 q-rows
  const bf16x8 bq0 = *(const bf16x8*)(Qh + (size_t)qrow * 64 + lg * 8);
  const bf16x8 bq1 = *(const bf16x8*)(Qh + (size_t)qrow * 64 + 32 + lg * 8);
  const int qj31 = (q0 & 31) + lr + 31;            // dx = qj31 - kj

  float ls = 0.f;
  __syncthreads();

  // ---- PHASE 1: wave-private K quarters; no intra-phase barriers ----
  const int srow8 = lane >> 3, sch = lane & 7;
  // prefetch tile it=0 (transient: 8 bf16x8 live one iteration)
  bf16x8 kpre[8];
#pragma unroll
  for (int i = 0; i < 8; ++i) {
    int row = i * 8 + srow8;
    kpre[i] = *(const bf16x8*)(Kh + (size_t)((w * 4) * 64 + row) * 64 + sch * 8);
  }
#pragma unroll
  for (int it = 0; it < 4; ++it) {
    const int gt = w * 4 + it;
#pragma unroll
    for (int i = 0; i < 8; ++i) {
      int row = i * 8 + srow8;
      *(bf16x8*)&KV[w][row][(sch ^ (row & 7)) * 8] = kpre[i];
    }
    if (it < 3) {
#pragma unroll
      for (int i = 0; i < 8; ++i) {
        int row = i * 8 + srow8;
        kpre[i] = *(const bf16x8*)(Kh + (size_t)((gt + 1) * 64 + row) * 64 + sch * 8);
      }
    }
    const bool bad = tbad[gt] != 0;
#pragma unroll
    for (int fn = 0; fn < 4; ++fn) {
      const unsigned short* krow = &KV[w][fn * 16 + lr][0];
      bf16x8 a0 = *(const bf16x8*)(krow + (lg ^ (lr & 7)) * 8);
      bf16x8 a1 = *(const bf16x8*)(krow + ((4 + lg) ^ (lr & 7)) * 8);
      f32x4 s = (f32x4){0.f, 0.f, 0.f, 0.f};
      s = __builtin_amdgcn_mfma_f32_16x16x32_bf16(a0, bq0, s, 0, 0, 0);
      s = __builtin_amdgcn_mfma_f32_16x16x32_bf16(a1, bq1, s, 0, 0, 0);
      u16x4 pb;
#pragma unroll
      for (int r = 0; r < 4; ++r) {
        int bidx = (31 - gt * 2 - (fn >> 1)) * 63 + qj31 - (fn & 1) * 16 - lg * 4 - r;
        float arg = fmaf(s[r], 0.125f, biasS[bidx]);
        if (bad) arg = fminf(arg, mbig[gt * 64 + fn * 16 + lg * 4 + r]);
        float p = __expf(arg);   // unnormalized P'
        ls += p;
        pb[r] = f2b(p);
      }
      int s8 = (gt * 16 + fn * 4 + lg) ^ ((lr & 7) << 1);
      *(u16x4*)((char*)&Pb[lr][0] + s8 * 8) = pb;   // row=q (lr), swizzled 8B slot
    }
  }
  ls += __shfl_xor(ls, 16, 64);
  ls += __shfl_xor(ls, 32, 64);
  if (lg == 0) lsbuf[w][lr] = ls;
  __syncthreads();   // Pb + lsbuf complete

  const float inv = 1.f / (lsbuf[0][lr] + lsbuf[1][lr] + lsbuf[2][lr] + lsbuf[3][lr]);

  // ---- PHASE 2a: normalized attention stores (wave w -> its k-quarter) ----
  f32x4 invs;
#pragma unroll
  for (int j = 0; j < 4; ++j) invs[j] = __shfl(inv, j * 4 + lg, 64);
  float* oa = out_attn + (size_t)bh * (S_ * S_) + (size_t)q0 * S_ + w * 256;
#pragma unroll
  for (int i = 0; i < 16; ++i) {
    int qv = (i & 3) * 4 + lg;
    int kk = (i >> 2) * 64 + lr * 4;
    int s8 = ((w * 256 + kk) >> 2) ^ ((qv & 7) << 1);
    u16x4 pb = *(const u16x4*)((const char*)&Pb[qv][0] + s8 * 8);
    f32x4 pr;
#pragma unroll
    for (int r = 0; r < 4; ++r) pr[r] = b2f(pb[r]) * invs[i & 3];
    *(f32x4*)(oa + (size_t)qv * S_ + kk) = pr;
  }

  // ---- PHASE 2b: PV, waves split by d-slice; V^T staged wave-privately into KV[w] ----
  f32x4 of = (f32x4){0.f, 0.f, 0.f, 0.f};
  bf16x8 vp0 = *(const bf16x8*)(Vth + (size_t)(w * 16 + (lane >> 3)) * S_ + (lane & 7) * 8);
  bf16x8 vp1 = *(const bf16x8*)(Vth + (size_t)(w * 16 + 8 + (lane >> 3)) * S_ + (lane & 7) * 8);
#pragma unroll
  for (int gt = 0; gt < 16; ++gt) {
    {
      int row0 = lane >> 3, ch = lane & 7;
      *(bf16x8*)&KV[w][row0][(ch ^ (row0 & 7)) * 8] = vp0;
      int row1 = 8 + (lane >> 3);
      *(bf16x8*)&KV[w][row1][(ch ^ (row1 & 7)) * 8] = vp1;
    }
    if (gt < 15) {
      vp0 = *(const bf16x8*)(Vth + (size_t)(w * 16 + (lane >> 3)) * S_ + (gt + 1) * 64 + (lane & 7) * 8);
      vp1 = *(const bf16x8*)(Vth + (size_t)(w * 16 + 8 + (lane >> 3)) * S_ + (gt + 1) * 64 + (lane & 7) * 8);
    }
#pragma unroll
    for (int sub = 0; sub < 2; ++sub) {
      int c16 = (gt * 8 + sub * 4 + lg) ^ (lr & 7);
      bf16x8 pa = *(const bf16x8*)((const char*)&Pb[lr][0] + c16 * 16);
      bf16x8 bv = *(const bf16x8*)((const char*)&KV[w][lr][0] + ((sub * 4 + lg) ^ (lr & 7)) * 16);
      of = __builtin_amdgcn_mfma_f32_16x16x32_bf16(pa, bv, of, 0, 0, 0);
    }
  }

  // ---- epilogue: O rows scaled by their own inv; Xp bf16 [B,S,D] ----
  f32x4 invq;
#pragma unroll
  for (int r = 0; r < 4; ++r) invq[r] = __shfl(inv, lg * 4 + r, 64);
#pragma unroll
  for (int r = 0; r < 4; ++r) {
    int q = q0 + lg * 4 + r;
    Xp[((size_t)b * S_ + q) * D_ + h * 64 + w * 16 + lr] = f2b(of[r] * invq[r]);
  }
}

// ---------------- host launch ----------------
extern "C" void kernel_launch(void* const* d_in, const int* in_sizes, int n_in,
                              void* d_out, int out_size, void* d_ws, size_t ws_size,
                              hipStream_t stream) {
  const float* query = (const float*)d_in[0];
  const float* key   = (const float*)d_in[1];
  const float* value = (const float*)d_in[2];
  const int*   maskp = (const int*)d_in[3];
  const float* Wq = (const float*)d_in[4];
  const float* bq = (const float*)d_in[5];
  const float* Wk = (const float*)d_in[6];
  const float* bk = (const float*)d_in[7];
  const float* Wv = (const float*)d_in[8];
  const float* bv = (const float*)d_in[9];
  const float* Wo = (const float*)d_in[10];
  const float* bo = (const float*)d_in[11];
  const float* W1 = (const float*)d_in[12];
  const float* b1 = (const float*)d_in[13];
  const float* W2 = (const float*)d_in[14];
  const float* b2 = (const float*)d_in[15];

  char* ws = (char*)d_ws;
  const size_t MB4 = (size_t)4 * 1024 * 1024;
  unsigned short* Qb  = (unsigned short*)(ws);
  unsigned short* Kb  = (unsigned short*)(ws + MB4);
  unsigned short* VT  = (unsigned short*)(ws + 2 * MB4);
  unsigned short* Xp  = (unsigned short*)(ws + 3 * MB4);
  unsigned short* WqT = (unsigned short*)(ws + 4 * MB4);
  unsigned short* WkT = (unsigned short*)(ws + 4 * MB4 + 524288);
  unsigned short* WvT = (unsigned short*)(ws + 4 * MB4 + 2 * 524288);
  unsigned short* WoT = (unsigned short*)(ws + 4 * MB4 + 3 * 524288);
  float* table        = (float*)(ws + 4 * MB4 + 4 * 524288);

  float* out_x = (float*)d_out;
  float* out_attn = out_x + (size_t)B_ * S_ * D_;

  k_prep<<<dim3(16, 16, 5), 256, 0, stream>>>(Wq, Wk, Wv, Wo, WqT, WkT, WvT, WoT,
                                              W1, b1, W2, b2, table);
  k_gemm_qkv<<<dim3(64, 4, 3), 256, 0, stream>>>(query, key, value, WqT, WkT, WvT,
                                                 bq, bk, bv, Qb, Kb, VT);
  k_attn<<<dim3(64, 32), 256, 0, stream>>>(Qb, Kb, VT, table, maskp, out_attn, Xp);
  k_gemm_out<<<dim3(64, 4), 256, 0, stream>>>(Xp, WoT, bo, out_x);
}